// Round 1
// baseline (406.999 us; speedup 1.0000x reference)
//
#include <hip/hip_runtime.h>

typedef __bf16 bf16;
typedef __bf16 bf16x8 __attribute__((ext_vector_type(8)));
typedef float  f32x4  __attribute__((ext_vector_type(4)));

#define DIM   1024
#define NH    16
#define NKV   4
#define HD    64
#define SLEN  264
#define BTOT  64            // B*T
#define MROWS (BTOT * SLEN) // 16896
#define NQKV  1536          // 1024 q + 256 k + 256 v
#define NZ    256

// ---------------- async global->LDS (wave-uniform base + lane*16) ----------------
__device__ __forceinline__ void gl_lds16(const bf16* g, bf16* l) {
    __builtin_amdgcn_global_load_lds((__attribute__((address_space(1))) void*)(g),
                                     (__attribute__((address_space(3))) void*)(l),
                                     16, 0, 0);
}

// ---------------- f32 -> bf16 converters ----------------
__global__ void cvt_f32_bf16(const float* __restrict__ src, bf16* __restrict__ dst, int n) {
    int i = (blockIdx.x * 256 + threadIdx.x) * 4;
    if (i < n) {
        float4 v = *(const float4*)(src + i);
        dst[i + 0] = (bf16)v.x; dst[i + 1] = (bf16)v.y;
        dst[i + 2] = (bf16)v.z; dst[i + 3] = (bf16)v.w;
    }
}

__global__ void cvt_wcat(const float* __restrict__ wq, const float* __restrict__ wk,
                         const float* __restrict__ wv, bf16* __restrict__ dst) {
    int i = (blockIdx.x * 256 + threadIdx.x) * 4;   // total 1536*1024
    const float* src; int off;
    if (i < 1024 * 1024)      { src = wq; off = i; }
    else if (i < 1280 * 1024) { src = wk; off = i - 1024 * 1024; }
    else                      { src = wv; off = i - 1280 * 1024; }
    float4 v = *(const float4*)(src + off);
    dst[i + 0] = (bf16)v.x; dst[i + 1] = (bf16)v.y;
    dst[i + 2] = (bf16)v.z; dst[i + 3] = (bf16)v.w;
}

// ---------------- m97-pattern GEMM: C[M,N] = A[M,K] @ B[N,K]^T ----------------
// 128x128 tile, BK=32, 4 waves in 2x2, each wave 4x4 tiles of 16x16x32 bf16 MFMA.
template <bool OUTBF>
__global__ __launch_bounds__(256) void gemm_bt(const bf16* __restrict__ A,
                                               const bf16* __restrict__ Bw,
                                               void* __restrict__ Cout,
                                               int Nld, int K) {
    __shared__ __align__(16) bf16 As[128 * 32];
    __shared__ __align__(16) bf16 Bs[128 * 32];
    const int tid  = threadIdx.x;
    const int wid  = tid >> 6, lane = tid & 63;
    const int quad = lane >> 4, r16 = lane & 15;
    const int bm = blockIdx.x, bn = blockIdx.y;
    const int wm = wid & 1, wn = wid >> 1;

    const bf16* Ag = A  + (size_t)(bm * 128 + (tid >> 2)) * K + (tid & 3) * 8;
    const bf16* Bg = Bw + (size_t)(bn * 128 + (tid >> 2)) * K + (tid & 3) * 8;
    bf16* AsW = As + wid * 512;   // bytes: 1024*wid (lane l writes +16*l)
    bf16* BsW = Bs + wid * 512;

    f32x4 acc[4][4];
#pragma unroll
    for (int i = 0; i < 4; i++)
#pragma unroll
        for (int j = 0; j < 4; j++) acc[i][j] = (f32x4){0.f, 0.f, 0.f, 0.f};

    for (int k0 = 0; k0 < K; k0 += 32) {
        __syncthreads();                       // LDS reuse fence
        gl_lds16(Ag + k0,           AsW);          // rows 0..63
        gl_lds16(Ag + 64 * K + k0,  AsW + 2048);   // rows 64..127
        gl_lds16(Bg + k0,           BsW);
        gl_lds16(Bg + 64 * K + k0,  BsW + 2048);
        __syncthreads();                       // drains vmcnt before use

        bf16x8 a[4], b[4];
#pragma unroll
        for (int i = 0; i < 4; i++) {
            a[i] = *(const bf16x8*)&As[(wm * 64 + i * 16 + r16) * 32 + quad * 8];
            b[i] = *(const bf16x8*)&Bs[(wn * 64 + i * 16 + r16) * 32 + quad * 8];
        }
#pragma unroll
        for (int i = 0; i < 4; i++)
#pragma unroll
            for (int j = 0; j < 4; j++)
                acc[i][j] = __builtin_amdgcn_mfma_f32_16x16x32_bf16(a[i], b[j], acc[i][j], 0, 0, 0);
    }

    // C/D layout: col = lane&15, row = quad*4 + r   [m89-verified]
#pragma unroll
    for (int i = 0; i < 4; i++)
#pragma unroll
        for (int j = 0; j < 4; j++)
#pragma unroll
            for (int r = 0; r < 4; r++) {
                int gm = bm * 128 + wm * 64 + i * 16 + quad * 4 + r;
                int gn = bn * 128 + wn * 64 + j * 16 + r16;
                float v = acc[i][j][r];
                if (OUTBF) ((bf16*)Cout)[(size_t)gm * Nld + gn] = (bf16)v;
                else       ((float*)Cout)[(size_t)gm * Nld + gn] = v;
            }
}

// ---------------- fused QKNorm + 2D-RoPE + soft-capped GQA attention ----------------
// grid (qchunk=5, kv=4, bt=64); block 256 = 4 waves; wave w handles q-head kv*4+w,
// all waves share the same 64-query chunk and the K/V LDS staging.
// Softcap bounds logits to +-50 => exp() safe in f32 => no online-softmax rescaling.
__global__ __launch_bounds__(256, 2) void attn_kernel(const bf16* __restrict__ qkv,
                                                      const float* __restrict__ qw,
                                                      const float* __restrict__ kw,
                                                      bf16* __restrict__ aout) {
    const int KLD = 72;  // 144B row stride: bank-stride 4, ~2-way on b128
    const int VLD = 40;  // 80B: bank-stride 20
    const int PLD = 40;
    __shared__ __align__(16) bf16 Ks[32 * 72];
    __shared__ __align__(16) bf16 Vt[64 * 40];
    __shared__ __align__(16) bf16 Pb[4 * 16 * 40];

    const int tid = threadIdx.x;
    const int wid = tid >> 6, lane = tid & 63;
    const int quad = lane >> 4, r16 = lane & 15;
    const int qc = blockIdx.x, kv = blockIdx.y, bt = blockIdx.z;
    const int h = kv * 4 + wid;
    const float LN1 = 0.5756462732485115f;  // ln(10000)/16

    // ---- per-wave Q fragments: load + RMSNorm + RoPE, keep in registers ----
    // A-layout: A[m=lane&15][k=quad*8+j], two k-steps (d<32, d>=32)
    bf16x8 qa[4][2];
    float  lsum[4][4];
    f32x4  oacc[4][4];
#pragma unroll
    for (int i = 0; i < 4; i++)
#pragma unroll
        for (int j = 0; j < 4; j++) { oacc[i][j] = (f32x4){0.f, 0.f, 0.f, 0.f}; lsum[i][j] = 0.f; }

    float qw0[8], qw1[8];
#pragma unroll
    for (int j = 0; j < 8; j++) { qw0[j] = qw[quad * 8 + j]; qw1[j] = qw[quad * 8 + 32 + j]; }

#pragma unroll
    for (int qt = 0; qt < 4; ++qt) {
        int q = qc * 64 + qt * 16 + r16;
        int qcl = q < 264 ? q : 263;  // clamp padded rows (masked at write)
        const bf16* src = qkv + (size_t)(bt * SLEN + qcl) * NQKV + h * HD + quad * 8;
        bf16x8 v0 = *(const bf16x8*)(src);
        bf16x8 v1 = *(const bf16x8*)(src + 32);
        float x0[8], x1[8], ss = 0.f;
#pragma unroll
        for (int j = 0; j < 8; j++) {
            x0[j] = (float)v0[j]; x1[j] = (float)v1[j];
            ss += x0[j] * x0[j] + x1[j] * x1[j];
        }
        ss += __shfl_xor(ss, 16, 64);
        ss += __shfl_xor(ss, 32, 64);
        float rms = rsqrtf(ss * (1.f / 64.f) + 1e-6f);
#pragma unroll
        for (int j = 0; j < 8; j++) { x0[j] *= rms * qw0[j]; x1[j] *= rms * qw1[j]; }
        if (q < NZ) {  // partial 2D RoPE on latent tokens only
            float rp = (float)(q >> 4), cp = (float)(q & 15);
#pragma unroll
            for (int j = 0; j < 8; j++) {
                int d = quad * 8 + j;                       // 0..31
                float ang = (d < 16 ? rp : cp) * __expf(-(float)(d & 15) * LN1);
                float sn, cs; __sincosf(ang, &sn, &cs);
                float y0 = x0[j] * cs - x1[j] * sn;          // d<32: -x[d+32]*sin
                float y1 = x1[j] * cs + x0[j] * sn;          // d>=32: +x[d-32]*sin
                x0[j] = y0; x1[j] = y1;
            }
        }
#pragma unroll
        for (int j = 0; j < 8; j++) { qa[qt][0][j] = (bf16)x0[j]; qa[qt][1][j] = (bf16)x1[j]; }
    }

    // staging roles
    const int krow = tid >> 3, part = tid & 7;
    float kw8[8];
#pragma unroll
    for (int j = 0; j < 8; j++) kw8[j] = kw[part * 8 + j];

    for (int c = 0; c < 9; ++c) {  // 264 keys = 8 full chunks of 32 + tail
        __syncthreads();
        { // ---- stage K chunk: RMSNorm + RoPE -> Ks[32][KLD], bf16 ----
            int key = c * 32 + krow;
            int keyc = key < 264 ? key : 263;
            const bf16* src = qkv + (size_t)(bt * SLEN + keyc) * NQKV + (NH * HD) + kv * HD + part * 8;
            bf16x8 kvv = *(const bf16x8*)src;
            float x[8], ss = 0.f;
#pragma unroll
            for (int j = 0; j < 8; j++) { x[j] = (float)kvv[j]; ss += x[j] * x[j]; }
            ss += __shfl_xor(ss, 1, 64);
            ss += __shfl_xor(ss, 2, 64);
            ss += __shfl_xor(ss, 4, 64);
            float rms = rsqrtf(ss * (1.f / 64.f) + 1e-6f);
#pragma unroll
            for (int j = 0; j < 8; j++) x[j] *= rms * kw8[j];
            float px[8];
#pragma unroll
            for (int j = 0; j < 8; j++) px[j] = __shfl_xor(x[j], 4, 64);  // rope partner (d +-32)
            if (key < NZ) {
                float rp = (float)(key >> 4), cp = (float)(key & 15);
#pragma unroll
                for (int j = 0; j < 8; j++) {
                    int d = part * 8 + j;                   // 0..63
                    float ang = (((d & 31) < 16) ? rp : cp) * __expf(-(float)(d & 15) * LN1);
                    float sn, cs; __sincosf(ang, &sn, &cs);
                    x[j] = (d < 32) ? (x[j] * cs - px[j] * sn) : (x[j] * cs + px[j] * sn);
                }
            }
            bf16x8 outv;
#pragma unroll
            for (int j = 0; j < 8; j++) outv[j] = (bf16)x[j];
            *(bf16x8*)&Ks[krow * KLD + part * 8] = outv;
        }
        { // ---- stage V chunk transposed: Vt[d][key], zero pad keys >= 264 ----
            int key = c * 32 + krow;
            int keyc = key < 264 ? key : 263;
            const bf16* src = qkv + (size_t)(bt * SLEN + keyc) * NQKV + (NH * HD + NKV * HD) + kv * HD + part * 8;
            bf16x8 vv = *(const bf16x8*)src;
            bool valid = key < 264;
#pragma unroll
            for (int j = 0; j < 8; j++)
                Vt[(part * 8 + j) * VLD + krow] = valid ? vv[j] : (bf16)0.f;
        }
        __syncthreads();

        // ---- compute ----
        const bool has1 = (c < 8);  // tile kt1 of tail chunk is fully OOB -> zeros
        bf16x8 bk[2][2];
#pragma unroll
        for (int kt = 0; kt < 2; ++kt)
#pragma unroll
            for (int st = 0; st < 2; ++st)
                bk[kt][st] = *(const bf16x8*)&Ks[(kt * 16 + r16) * KLD + st * 32 + quad * 8];
        bf16x8 bv[4];
#pragma unroll
        for (int dt = 0; dt < 4; ++dt)
            bv[dt] = *(const bf16x8*)&Vt[(dt * 16 + r16) * VLD + quad * 8];

        bf16* Pw = Pb + wid * 16 * PLD;  // per-wave P buffer: no barrier needed
#pragma unroll
        for (int qt = 0; qt < 4; ++qt) {
            f32x4 s0 = (f32x4){0.f, 0.f, 0.f, 0.f};
            s0 = __builtin_amdgcn_mfma_f32_16x16x32_bf16(qa[qt][0], bk[0][0], s0, 0, 0, 0);
            s0 = __builtin_amdgcn_mfma_f32_16x16x32_bf16(qa[qt][1], bk[0][1], s0, 0, 0, 0);
            f32x4 s1 = (f32x4){0.f, 0.f, 0.f, 0.f};
            if (has1) {
                s1 = __builtin_amdgcn_mfma_f32_16x16x32_bf16(qa[qt][0], bk[1][0], s1, 0, 0, 0);
                s1 = __builtin_amdgcn_mfma_f32_16x16x32_bf16(qa[qt][1], bk[1][1], s1, 0, 0, 0);
            }
#pragma unroll
            for (int r = 0; r < 4; ++r) {
                int prow = quad * 4 + r;
                {   // key tile kt0: cols c*32 + r16
                    int key = c * 32 + r16;
                    float sr = s0[r] * 0.125f;
                    float e  = __expf(sr * 0.04f);           // tanh(sr/50) via exp(2x)
                    float th = (e - 1.f) / (e + 1.f);
                    float p  = __expf(50.f * th);
                    p = (key < 264) ? p : 0.f;
                    bf16 pbv = (bf16)p;
                    lsum[qt][r] += (float)pbv;               // match PV's bf16 weights
                    Pw[prow * PLD + r16] = pbv;
                }
                {   // key tile kt1: cols c*32 + 16 + r16
                    float p = 0.f;
                    if (has1) {
                        float sr = s1[r] * 0.125f;
                        float e  = __expf(sr * 0.04f);
                        float th = (e - 1.f) / (e + 1.f);
                        p = __expf(50.f * th);
                    }
                    bf16 pbv = (bf16)p;
                    lsum[qt][r] += (float)pbv;
                    Pw[prow * PLD + 16 + r16] = pbv;
                }
            }
            // P: C-layout -> A-layout via per-wave LDS round trip (m120 pattern)
            bf16x8 pa = *(const bf16x8*)&Pw[r16 * PLD + quad * 8];
#pragma unroll
            for (int dt = 0; dt < 4; ++dt)
                oacc[qt][dt] = __builtin_amdgcn_mfma_f32_16x16x32_bf16(pa, bv[dt], oacc[qt][dt], 0, 0, 0);
        }
    }

    // ---- finalize: reduce l over the 16 cols (lanes sharing quad), divide, store ----
#pragma unroll
    for (int qt = 0; qt < 4; ++qt)
#pragma unroll
        for (int r = 0; r < 4; ++r) {
            float l = lsum[qt][r];
            l += __shfl_xor(l, 1, 64);
            l += __shfl_xor(l, 2, 64);
            l += __shfl_xor(l, 4, 64);
            l += __shfl_xor(l, 8, 64);
            lsum[qt][r] = l;
        }
#pragma unroll
    for (int qt = 0; qt < 4; ++qt)
#pragma unroll
        for (int r = 0; r < 4; ++r) {
            int q = qc * 64 + qt * 16 + quad * 4 + r;
            if (q < 264) {
                float inv = 1.f / lsum[qt][r];
                size_t base = (size_t)(bt * SLEN + q) * (NH * HD) + h * HD;
#pragma unroll
                for (int dt = 0; dt < 4; ++dt)
                    aout[base + dt * 16 + r16] = (bf16)(oacc[qt][dt][r] * inv);
            }
        }
}

// ---------------- launcher ----------------
extern "C" void kernel_launch(void* const* d_in, const int* in_sizes, int n_in,
                              void* d_out, int out_size, void* d_ws, size_t ws_size,
                              hipStream_t stream) {
    const float* x   = (const float*)d_in[0];
    const float* wq  = (const float*)d_in[1];
    const float* wk  = (const float*)d_in[2];
    const float* wv  = (const float*)d_in[3];
    const float* wo  = (const float*)d_in[4];
    const float* qnw = (const float*)d_in[5];
    const float* knw = (const float*)d_in[6];

    bf16* xbf  = (bf16*)d_ws;                        // 16896x1024
    bf16* wcat = xbf  + (size_t)MROWS * DIM;         // 1536x1024  [wq;wk;wv]
    bf16* wobf = wcat + (size_t)NQKV * DIM;          // 1024x1024
    bf16* qkv  = wobf + (size_t)DIM * DIM;           // 16896x1536 (bf16)
    bf16* aout = qkv  + (size_t)MROWS * NQKV;        // 16896x1024 (bf16)
    // total ws use: ~120.5 MB

    cvt_f32_bf16<<<(MROWS * DIM) / 1024, 256, 0, stream>>>(x, xbf, MROWS * DIM);
    cvt_wcat<<<(NQKV * DIM) / 1024, 256, 0, stream>>>(wq, wk, wv, wcat);
    cvt_f32_bf16<<<(DIM * DIM) / 1024, 256, 0, stream>>>(wo, wobf, DIM * DIM);

    gemm_bt<true><<<dim3(MROWS / 128, NQKV / 128), 256, 0, stream>>>(xbf, wcat, qkv, NQKV, DIM);
    attn_kernel<<<dim3(5, NKV, BTOT), 256, 0, stream>>>(qkv, qnw, knw, aout);
    gemm_bt<false><<<dim3(MROWS / 128, DIM / 128), 256, 0, stream>>>(aout, wobf, d_out, DIM, DIM);
}